// Round 12
// baseline (147.519 us; speedup 1.0000x reference)
//
#include <hip/hip_runtime.h>
#include <hip/hip_bf16.h>

typedef __attribute__((ext_vector_type(8))) short bf16x8;
typedef __attribute__((ext_vector_type(4))) float f32x4;

#define BB 4
#define TT 16
#define NT0 12
#define LL 64
#define CC 512
#define HH 8
#define HD 64
#define NQ (NT0*LL)       // 768 queries per batch
#define NCTX (TT*LL)      // 1024 cross keys per batch

#define GPTR(x) ((__attribute__((address_space(1))) void*)(x))
#define SPTR(x) ((__attribute__((address_space(3))) void*)(x))
// waitcnt imm: vmcnt(n) in [3:0] (n<=15 here), lgkmcnt=15 (no wait), expcnt=7 (no wait)
#define VMCNT(n) (((n) & 15) | (7u << 4) | (0xFu << 8))

__device__ __forceinline__ float bf2f(ushort u) {
  union { unsigned int i; float f; } x; x.i = ((unsigned int)u) << 16; return x.f;
}
__device__ __forceinline__ ushort f2bf(float f) {
  union { float f; unsigned int i; } x; x.f = f;
  unsigned int r = x.i + 0x7fffu + ((x.i >> 16) & 1u);  // RNE
  return (ushort)(r >> 16);
}

// Convert f32 inputs -> bf16 workspace, layout [qkv_w|k_w|v_w|proj_w|x|x_ctx|dx_ctx].
// Skips x_ctx/dx_ctx frames whose ctx_mask is 0 (their kctx/vctx are never read).
__global__ __launch_bounds__(256) void cvt_all(const float* __restrict__ w0,
                                               const float* __restrict__ w1,
                                               const float* __restrict__ w2,
                                               const float* __restrict__ w3,
                                               const float* __restrict__ x,
                                               const float* __restrict__ xc,
                                               const float* __restrict__ dxc,
                                               const int* __restrict__ ctx_mask,
                                               ushort* __restrict__ dst) {
  long i = (long)blockIdx.x * 256 + threadIdx.x;  // float4 index, total 1835008
  const float* src; long off;
  if (i < 196608)       { src = w0;  off = 0; }
  else if (i < 262144)  { src = w1;  off = 196608; }
  else if (i < 327680)  { src = w2;  off = 262144; }
  else if (i < 393216)  { src = w3;  off = 327680; }
  else if (i < 786432)  { src = x;   off = 393216; }
  else if (i < 1310720) {
    int r = (int)((i - 786432) >> 7);            // row in (4096, 512)
    if (ctx_mask[(r >> 10) * TT + ((r >> 6) & 15)] == 0) return;
    src = xc;  off = 786432;
  } else {
    int r = (int)((i - 1310720) >> 7);
    if (ctx_mask[(r >> 10) * TT + ((r >> 6) & 15)] == 0) return;
    src = dxc; off = 1310720;
  }
  f32x4 v = *(const f32x4*)(src + (i - off) * 4);
  ushort4 o = { f2bf(v[0]), f2bf(v[1]), f2bf(v[2]), f2bf(v[3]) };
  *(ushort4*)(dst + i * 4) = o;
}

// ---------------------------------------------------------------------------
// MTx128-tile GEMM block body (MT = 128 or 64), BK=32, TRIPLE-BUFFER depth-2
// (R10-proven): issue ks+2's loads, wait vmcnt(2L), raw s_barrier.
// ---------------------------------------------------------------------------
template<int MT>
__device__ __forceinline__ void gemm_mac(const ushort* __restrict__ A,
                                         const ushort* __restrict__ W,
                                         int mt, int nt, ushort* lds,
                                         f32x4* acc) {
  constexpr int ASZ = MT * 32;         // A ushorts per buf
  constexpr int BUF = ASZ + 4096;      // buf stride in ushorts
  constexpr int L   = (MT == 128) ? 4 : 3;  // loads per thread per stage

  int t = threadIdx.x;
  int pa0 = t, pa1 = t + 256;
  int ra0 = pa0 >> 2, ra1 = pa1 >> 2;
  int ca0 = (pa0 & 3) ^ ((ra0 >> 1) & 3);
  int ca1 = (pa1 & 3) ^ ((ra1 >> 1) & 3);
  const ushort* ga0 = A + (size_t)(mt * MT + ra0) * 512 + ca0 * 8;
  const ushort* ga1 = A + (size_t)(mt * MT + ra1) * 512 + ca1 * 8;
  const ushort* gw0 = W + (size_t)(nt * 128 + ra0) * 512 + ca0 * 8;
  const ushort* gw1 = W + (size_t)(nt * 128 + ra1) * 512 + ca1 * 8;

  int lane = t & 63, l15 = lane & 15, kg = lane >> 4;
  int wv = t >> 6;
  int mh = (wv >> 1) * (MT / 2), nh = (wv & 1) * 64;
  int swz = kg ^ ((l15 >> 1) & 3);
  int faoff = (mh + l15) * 32 + swz * 8;
  int fwoff = (nh + l15) * 32 + swz * 8;

  auto stage = [&](int ks, int bb) {
    int ko = ks * 32;
    __builtin_amdgcn_global_load_lds(GPTR(ga0 + ko), SPTR(lds + bb + pa0 * 8), 16, 0, 0);
    if (MT == 128)
      __builtin_amdgcn_global_load_lds(GPTR(ga1 + ko), SPTR(lds + bb + pa1 * 8), 16, 0, 0);
    __builtin_amdgcn_global_load_lds(GPTR(gw0 + ko), SPTR(lds + bb + ASZ + pa0 * 8), 16, 0, 0);
    __builtin_amdgcn_global_load_lds(GPTR(gw1 + ko), SPTR(lds + bb + ASZ + pa1 * 8), 16, 0, 0);
  };

  stage(0, 0);
  stage(1, BUF);

#pragma unroll
  for (int ks = 0; ks < 16; ++ks) {
    int cur = (ks % 3) * BUF;
    if (ks < 14) {
      stage(ks + 2, ((ks + 2) % 3) * BUF);
      __builtin_amdgcn_s_waitcnt(VMCNT(2 * L));
    } else if (ks == 14) {
      __builtin_amdgcn_s_waitcnt(VMCNT(L));
    } else {
      __builtin_amdgcn_s_waitcnt(VMCNT(0));
    }
    asm volatile("" ::: "memory");
    __builtin_amdgcn_s_barrier();
    asm volatile("" ::: "memory");

    const ushort* fa = lds + cur + faoff;
    const ushort* fw = lds + cur + ASZ + fwoff;
    bf16x8 af[MT / 32], wf[4];
#pragma unroll
    for (int i = 0; i < MT / 32; ++i) af[i] = *(const bf16x8*)(fa + i * 512);
#pragma unroll
    for (int i = 0; i < 4; ++i) wf[i] = *(const bf16x8*)(fw + i * 512);
#pragma unroll
    for (int mi = 0; mi < MT / 32; ++mi)
#pragma unroll
      for (int ni = 0; ni < 4; ++ni)
        acc[mi * 4 + ni] =
            __builtin_amdgcn_mfma_f32_16x16x32_bf16(af[mi], wf[ni], acc[mi * 4 + ni], 0, 0, 0);

    asm volatile("" ::: "memory");
    __builtin_amdgcn_s_barrier();
    asm volatile("" ::: "memory");
  }
}

// OUTMODE 0: C bf16 row-major [*,N]. 1: CT bf16 transposed CT[col*TM+row]
// (CT may be pre-offset). 2: Cf f32 row-major + bias.
template<int MT, int OUTMODE>
__device__ __forceinline__ void gemm_body(const ushort* __restrict__ A,
                                          const ushort* __restrict__ W,
                                          ushort* __restrict__ C,
                                          ushort* __restrict__ CT,
                                          float* __restrict__ Cf,
                                          const float* __restrict__ bias,
                                          int mt, int nt, int N, long TM,
                                          ushort* lds) {
  f32x4 acc[(MT / 32) * 4];
#pragma unroll
  for (int i = 0; i < (MT / 32) * 4; ++i) acc[i] = (f32x4){0, 0, 0, 0};
  gemm_mac<MT>(A, W, mt, nt, lds, acc);

  int lane = threadIdx.x & 63, l15 = lane & 15, kg = lane >> 4;
  int wv = threadIdx.x >> 6;
  int Rw = mt * MT + (wv >> 1) * (MT / 2);
  int Cw = nt * 128 + (wv & 1) * 64;
#pragma unroll
  for (int mi = 0; mi < MT / 32; ++mi) {
    int row = Rw + mi * 16 + kg * 4;
#pragma unroll
    for (int ni = 0; ni < 4; ++ni) {
      f32x4 v = acc[mi * 4 + ni];
      int col = Cw + ni * 16 + l15;
      if (OUTMODE == 0) {
#pragma unroll
        for (int r = 0; r < 4; ++r) C[(size_t)(row + r) * N + col] = f2bf(v[r]);
      } else if (OUTMODE == 1) {
        ushort4 o = { f2bf(v[0]), f2bf(v[1]), f2bf(v[2]), f2bf(v[3]) };
        *(ushort4*)(CT + (long)col * TM + row) = o;
      } else {
        float bv = bias[col];
#pragma unroll
        for (int r = 0; r < 4; ++r) Cf[(size_t)(row + r) * N + col] = v[r] + bv;
      }
    }
  }
}

// Fused input GEMMs. blocks [0,288): qkv = x@qkv_w.T (24m x 12n tiles;
// n-tiles >=8 are self-V cols -> transposed into vselfT).
// [288,416): kctx (32x4). [416,544): vctx^T (32x4). kctx/vctx tiles whose
// BOTH covered frames are masked exit before staging (never read by flash).
__global__ __launch_bounds__(256) void gemm3(const ushort* __restrict__ xb,
                                             const ushort* __restrict__ dxb,
                                             const ushort* __restrict__ xcb,
                                             const ushort* __restrict__ qkvwb,
                                             const ushort* __restrict__ kwb,
                                             const ushort* __restrict__ vwb,
                                             const int* __restrict__ ctx_mask,
                                             ushort* __restrict__ qkv,
                                             ushort* __restrict__ vselfT,
                                             ushort* __restrict__ kctx,
                                             ushort* __restrict__ vctxT) {
  __shared__ ushort lds[24576];   // 3 bufs x (A 8KB + W 8KB) = 48 KB
  int blk = blockIdx.x;
  if (blk < 288) {
    int mt = blk % 24, nt = blk / 24;
    if (nt < 8)
      gemm_body<128, 0>(xb, qkvwb, qkv, nullptr, nullptr, nullptr, mt, nt, 1536, 0, lds);
    else
      gemm_body<128, 1>(xb, qkvwb, nullptr, vselfT - (size_t)1024 * 3072, nullptr, nullptr,
                        mt, nt, 1536, 3072, lds);
  } else if (blk < 416) {
    int r = blk - 288;
    int mt = r % 32, nt = r / 32;
    int bb = mt >> 3, f0 = (mt & 7) << 1;
    if (ctx_mask[bb * TT + f0] == 0 && ctx_mask[bb * TT + f0 + 1] == 0) return;
    gemm_body<128, 0>(dxb, kwb, kctx, nullptr, nullptr, nullptr, mt, nt, 512, 0, lds);
  } else {
    int r = blk - 416;
    int mt = r % 32, nt = r / 32;
    int bb = mt >> 3, f0 = (mt & 7) << 1;
    if (ctx_mask[bb * TT + f0] == 0 && ctx_mask[bb * TT + f0 + 1] == 0) return;
    gemm_body<128, 1>(xcb, vwb, nullptr, vctxT, nullptr, nullptr, mt, nt, 512, 4096, lds);
  }
}

// proj: 64-row tiles -> 192 blocks (48 mt x 4 nt).
__global__ __launch_bounds__(256) void gemm_proj(const ushort* __restrict__ aout,
                                                 const ushort* __restrict__ pwb,
                                                 const float* __restrict__ bias,
                                                 float* __restrict__ out) {
  __shared__ ushort lds[18432];   // 3 bufs x (A 4KB + W 8KB) = 36 KB
  int blk = blockIdx.x;
  gemm_body<64, 2>(aout, pwb, nullptr, nullptr, out, bias, blk % 48, blk / 48, 512, 0, lds);
}

// One attention tile for a 64-query wave: one K/V fragment stream feeds FOUR
// 16-query S^T/PV chains. Per-st processing keeps only 16 score regs live.
__device__ __forceinline__ void attn_tile64(const ushort* __restrict__ kbase, int kstr,
                                            const ushort* __restrict__ vtb, int vtN,
                                            const bf16x8* q0, const bf16x8* q1,
                                            int l15, int kg,
                                            ushort* __restrict__ Pt,
                                            f32x4 (*acc)[4], float* Lacc) {
#pragma unroll
  for (int st = 0; st < 4; ++st) {
    const ushort* kp = kbase + (size_t)(st * 16 + l15) * kstr + kg * 8;
    bf16x8 k0 = *(const bf16x8*)kp;
    bf16x8 k1 = *(const bf16x8*)(kp + 32);
    f32x4 z[4];
#pragma unroll
    for (int qf = 0; qf < 4; ++qf) {
      f32x4 t = {0, 0, 0, 0};
      t = __builtin_amdgcn_mfma_f32_16x16x32_bf16(k0, q0[qf], t, 0, 0, 0);
      t = __builtin_amdgcn_mfma_f32_16x16x32_bf16(k1, q1[qf], t, 0, 0, 0);
      z[qf] = t;
    }
#pragma unroll
    for (int qf = 0; qf < 4; ++qf) {
      float p0 = __builtin_exp2f(fmaf(z[qf][0], 0.18033688f, -23.0831206f));
      float p1 = __builtin_exp2f(fmaf(z[qf][1], 0.18033688f, -23.0831206f));
      float p2 = __builtin_exp2f(fmaf(z[qf][2], 0.18033688f, -23.0831206f));
      float p3 = __builtin_exp2f(fmaf(z[qf][3], 0.18033688f, -23.0831206f));
      Lacc[qf] += (p0 + p1) + (p2 + p3);
      ushort4 pk = { f2bf(p0), f2bf(p1), f2bf(p2), f2bf(p3) };
      *(ushort4*)(Pt + qf * 1152 + l15 * 72 + st * 16 + kg * 4) = pk;
    }
  }
#pragma unroll
  for (int kc = 0; kc < 2; ++kc) {
    bf16x8 pb[4];
#pragma unroll
    for (int qf = 0; qf < 4; ++qf)
      pb[qf] = *(const bf16x8*)(Pt + qf * 1152 + l15 * 72 + kc * 32 + kg * 8);
#pragma unroll
    for (int d = 0; d < 4; ++d) {
      const ushort* vp = vtb + (size_t)(d * 16 + l15) * vtN + kc * 32 + kg * 8;
      bf16x8 vf = *(const bf16x8*)vp;
#pragma unroll
      for (int qf = 0; qf < 4; ++qf)
        acc[qf][d] = __builtin_amdgcn_mfma_f32_16x16x32_bf16(vf, pb[qf], acc[qf][d], 0, 0, 0);
    }
  }
}

// Flash attention, fixed-M streaming softmax, 4-way split-K, 64-query waves.
// Block = (b, h, t0): 384 blocks x 256 threads = 4 key-split waves, each
// carrying the frame's full 64 queries (4 Q-frags). Merge = plain sums.
__global__ __launch_bounds__(256) void flash_attn(const ushort* __restrict__ qkv,
                                                  const ushort* __restrict__ kctx,
                                                  const ushort* __restrict__ vctxT,
                                                  const ushort* __restrict__ vselfT,
                                                  const int* __restrict__ ctx_mask,
                                                  ushort* __restrict__ aout) {
  __shared__ float smem[13056];      // 52.2 KB; Pt strips (36.9 KB) alias low part
  int blk = blockIdx.x;              // b*96 + h*12 + t0
  int t0 = blk % NT0;
  int h  = (blk / NT0) % HH;
  int b  = blk / (NT0 * HH);
  int tid = threadIdx.x, ks = tid >> 6, lane = tid & 63;
  int l15 = lane & 15, kg = lane >> 4;

  int qbase = b * NQ + t0 * LL;
  bf16x8 q0[4], q1[4];
#pragma unroll
  for (int qf = 0; qf < 4; ++qf) {
    const ushort* qp = qkv + (size_t)(qbase + qf * 16 + l15) * 1536 + h * HD + kg * 8;
    q0[qf] = *(const bf16x8*)qp;
    q1[qf] = *(const bf16x8*)(qp + 32);
  }

  f32x4 acc[4][4];
#pragma unroll
  for (int qf = 0; qf < 4; ++qf)
#pragma unroll
    for (int d = 0; d < 4; ++d) acc[qf][d] = (f32x4){0, 0, 0, 0};
  float Lacc[4] = {0.f, 0.f, 0.f, 0.f};
  ushort* Pt = (ushort*)smem + ks * 4608;  // 4 strips of 1152 ushorts

  int kts[4]; int nkt = 0;
#pragma unroll
  for (int ki = 0; ki < 4; ++ki) {
    int kt = ks * 4 + ki;
    if (ctx_mask[b * TT + kt] != 0 && kt != t0 + 4) kts[nkt++] = kt;
  }

  const ushort* vctxb = vctxT + (size_t)h * HD * (BB * NCTX) + b * NCTX;
  for (int ki = 0; ki < nkt; ++ki) {
    int kt = kts[ki];
    attn_tile64(kctx + (size_t)(b * NCTX + kt * LL) * CC + h * HD, CC,
                vctxb + kt * LL, BB * NCTX,
                q0, q1, l15, kg, Pt, acc, Lacc);
  }
  if (ks == 0) {
    attn_tile64(qkv + (size_t)(b * NQ + t0 * LL) * 1536 + CC + h * HD, 1536,
                vselfT + (size_t)h * HD * (BB * NQ) + b * NQ + t0 * LL, BB * NQ,
                q0, q1, l15, kg, Pt, acc, Lacc);
  }

  float L[4];
#pragma unroll
  for (int qf = 0; qf < 4; ++qf) {
    float v = Lacc[qf];
    v += __shfl_xor(v, 16, 64);
    v += __shfl_xor(v, 32, 64);
    L[qf] = v;
  }

  // ---- merge: ks1..3 publish (plain sums), ks0 adds & writes ----
  __syncthreads();
  if (ks) {
    float* reg = smem + (size_t)(ks - 1) * 4352;  // 4096 acc + 256 L
#pragma unroll
    for (int qf = 0; qf < 4; ++qf)
#pragma unroll
      for (int d = 0; d < 4; ++d)
        *(f32x4*)(reg + (qf * 64 + lane) * 16 + d * 4) = acc[qf][d];
#pragma unroll
    for (int qf = 0; qf < 4; ++qf) reg[4096 + qf * 64 + lane] = L[qf];
  }
  __syncthreads();
  if (!ks) {
#pragma unroll
    for (int j = 0; j < 3; ++j) {
      const float* reg = smem + (size_t)j * 4352;
#pragma unroll
      for (int qf = 0; qf < 4; ++qf) {
        L[qf] += reg[4096 + qf * 64 + lane];
#pragma unroll
        for (int d = 0; d < 4; ++d)
          acc[qf][d] += *(const f32x4*)(reg + (qf * 64 + lane) * 16 + d * 4);
      }
    }
#pragma unroll
    for (int qf = 0; qf < 4; ++qf) {
      float inv = 1.f / L[qf];
      int orow = qbase + qf * 16 + l15;
#pragma unroll
      for (int d = 0; d < 4; ++d) {
        ushort4 ov = { f2bf(acc[qf][d][0] * inv), f2bf(acc[qf][d][1] * inv),
                       f2bf(acc[qf][d][2] * inv), f2bf(acc[qf][d][3] * inv) };
        *(ushort4*)(aout + (size_t)orow * CC + h * HD + d * 16 + kg * 4) = ov;
      }
    }
  }
}

extern "C" void kernel_launch(void* const* d_in, const int* in_sizes, int n_in,
                              void* d_out, int out_size, void* d_ws, size_t ws_size,
                              hipStream_t stream) {
  const float* x        = (const float*)d_in[0];
  const float* x_ctx    = (const float*)d_in[1];
  const float* dx_ctx   = (const float*)d_in[2];
  const int*   ctx_mask = (const int*)d_in[3];
  const float* qkv_w    = (const float*)d_in[4];
  const float* k_w      = (const float*)d_in[5];
  const float* v_w      = (const float*)d_in[6];
  const float* proj_w   = (const float*)d_in[7];
  const float* proj_b   = (const float*)d_in[8];
  float* out = (float*)d_out;

  ushort* ws = (ushort*)d_ws;   // element offsets (bf16)
  ushort* qkvwb  = ws;                    //  786432
  ushort* kwb    = ws + 786432;           //  262144
  ushort* vwb    = ws + 1048576;          //  262144
  ushort* pwb    = ws + 1310720;          //  262144
  ushort* xb     = ws + 1572864;          // 1572864  (3072x512)
  ushort* xcb    = ws + 3145728;          // 2097152  (4096x512)
  ushort* dxb    = ws + 5242880;          // 2097152  (4096x512)
  ushort* qkv    = ws + 7340032;          // 3072x1536
  ushort* kctx   = ws + 12058624;         // 4096x512
  ushort* vctxT  = ws + 14155776;         // 512x4096
  ushort* vselfT = ws + 16252928;         // 512x3072
  ushort* aout   = ws + 17825792;         // 3072x512  (end 19398656 el = 38.8MB)

  cvt_all<<<7168, 256, 0, stream>>>(qkv_w, k_w, v_w, proj_w, x, x_ctx, dx_ctx,
                                    ctx_mask, ws);
  gemm3<<<544, 256, 0, stream>>>(xb, dxb, xcb, qkvwb, kwb, vwb, ctx_mask,
                                 qkv, vselfT, kctx, vctxT);
  flash_attn<<<384, 256, 0, stream>>>(qkv, kctx, vctxT, vselfT, ctx_mask, aout);
  gemm_proj<<<192, 256, 0, stream>>>(aout, pwb, proj_b, out);
}

// Round 13
// 137.138 us; speedup vs baseline: 1.0757x; 1.0757x over previous
//
#include <hip/hip_runtime.h>
#include <hip/hip_bf16.h>

typedef __attribute__((ext_vector_type(8))) short bf16x8;
typedef __attribute__((ext_vector_type(4))) float f32x4;

#define BB 4
#define TT 16
#define NT0 12
#define LL 64
#define CC 512
#define HH 8
#define HD 64
#define NQ (NT0*LL)       // 768 queries per batch
#define NCTX (TT*LL)      // 1024 cross keys per batch

#define GPTR(x) ((__attribute__((address_space(1))) void*)(x))
#define SPTR(x) ((__attribute__((address_space(3))) void*)(x))
// waitcnt imm: vmcnt(n) in [3:0] (n<=15 here), lgkmcnt=15 (no wait), expcnt=7 (no wait)
#define VMCNT(n) (((n) & 15) | (7u << 4) | (0xFu << 8))

__device__ __forceinline__ float bf2f(ushort u) {
  union { unsigned int i; float f; } x; x.i = ((unsigned int)u) << 16; return x.f;
}
__device__ __forceinline__ ushort f2bf(float f) {
  union { float f; unsigned int i; } x; x.f = f;
  unsigned int r = x.i + 0x7fffu + ((x.i >> 16) & 1u);  // RNE
  return (ushort)(r >> 16);
}

// Convert f32 inputs -> bf16 workspace, layout [qkv_w|k_w|v_w|proj_w|x|x_ctx|dx_ctx].
// Skips x_ctx/dx_ctx frames whose ctx_mask is 0 (their kctx/vctx are never read).
__global__ __launch_bounds__(256) void cvt_all(const float* __restrict__ w0,
                                               const float* __restrict__ w1,
                                               const float* __restrict__ w2,
                                               const float* __restrict__ w3,
                                               const float* __restrict__ x,
                                               const float* __restrict__ xc,
                                               const float* __restrict__ dxc,
                                               const int* __restrict__ ctx_mask,
                                               ushort* __restrict__ dst) {
  long i = (long)blockIdx.x * 256 + threadIdx.x;  // float4 index, total 1835008
  const float* src; long off;
  if (i < 196608)       { src = w0;  off = 0; }
  else if (i < 262144)  { src = w1;  off = 196608; }
  else if (i < 327680)  { src = w2;  off = 262144; }
  else if (i < 393216)  { src = w3;  off = 327680; }
  else if (i < 786432)  { src = x;   off = 393216; }
  else if (i < 1310720) {
    int r = (int)((i - 786432) >> 7);            // row in (4096, 512)
    if (ctx_mask[(r >> 10) * TT + ((r >> 6) & 15)] == 0) return;
    src = xc;  off = 786432;
  } else {
    int r = (int)((i - 1310720) >> 7);
    if (ctx_mask[(r >> 10) * TT + ((r >> 6) & 15)] == 0) return;
    src = dxc; off = 1310720;
  }
  f32x4 v = *(const f32x4*)(src + (i - off) * 4);
  ushort4 o = { f2bf(v[0]), f2bf(v[1]), f2bf(v[2]), f2bf(v[3]) };
  *(ushort4*)(dst + i * 4) = o;
}

// ---------------------------------------------------------------------------
// MTx128-tile GEMM block body (MT = 128 or 64), BK=32, TRIPLE-BUFFER depth-2
// (R10-proven): issue ks+2's loads, wait vmcnt(2L), raw s_barrier.
// ---------------------------------------------------------------------------
template<int MT>
__device__ __forceinline__ void gemm_mac(const ushort* __restrict__ A,
                                         const ushort* __restrict__ W,
                                         int mt, int nt, ushort* lds,
                                         f32x4* acc) {
  constexpr int ASZ = MT * 32;         // A ushorts per buf
  constexpr int BUF = ASZ + 4096;      // buf stride in ushorts
  constexpr int L   = (MT == 128) ? 4 : 3;  // loads per thread per stage

  int t = threadIdx.x;
  int pa0 = t, pa1 = t + 256;
  int ra0 = pa0 >> 2, ra1 = pa1 >> 2;
  int ca0 = (pa0 & 3) ^ ((ra0 >> 1) & 3);
  int ca1 = (pa1 & 3) ^ ((ra1 >> 1) & 3);
  const ushort* ga0 = A + (size_t)(mt * MT + ra0) * 512 + ca0 * 8;
  const ushort* ga1 = A + (size_t)(mt * MT + ra1) * 512 + ca1 * 8;
  const ushort* gw0 = W + (size_t)(nt * 128 + ra0) * 512 + ca0 * 8;
  const ushort* gw1 = W + (size_t)(nt * 128 + ra1) * 512 + ca1 * 8;

  int lane = t & 63, l15 = lane & 15, kg = lane >> 4;
  int wv = t >> 6;
  int mh = (wv >> 1) * (MT / 2), nh = (wv & 1) * 64;
  int swz = kg ^ ((l15 >> 1) & 3);
  int faoff = (mh + l15) * 32 + swz * 8;
  int fwoff = (nh + l15) * 32 + swz * 8;

  auto stage = [&](int ks, int bb) {
    int ko = ks * 32;
    __builtin_amdgcn_global_load_lds(GPTR(ga0 + ko), SPTR(lds + bb + pa0 * 8), 16, 0, 0);
    if (MT == 128)
      __builtin_amdgcn_global_load_lds(GPTR(ga1 + ko), SPTR(lds + bb + pa1 * 8), 16, 0, 0);
    __builtin_amdgcn_global_load_lds(GPTR(gw0 + ko), SPTR(lds + bb + ASZ + pa0 * 8), 16, 0, 0);
    __builtin_amdgcn_global_load_lds(GPTR(gw1 + ko), SPTR(lds + bb + ASZ + pa1 * 8), 16, 0, 0);
  };

  stage(0, 0);
  stage(1, BUF);

#pragma unroll
  for (int ks = 0; ks < 16; ++ks) {
    int cur = (ks % 3) * BUF;
    if (ks < 14) {
      stage(ks + 2, ((ks + 2) % 3) * BUF);
      __builtin_amdgcn_s_waitcnt(VMCNT(2 * L));
    } else if (ks == 14) {
      __builtin_amdgcn_s_waitcnt(VMCNT(L));
    } else {
      __builtin_amdgcn_s_waitcnt(VMCNT(0));
    }
    asm volatile("" ::: "memory");
    __builtin_amdgcn_s_barrier();
    asm volatile("" ::: "memory");

    const ushort* fa = lds + cur + faoff;
    const ushort* fw = lds + cur + ASZ + fwoff;
    bf16x8 af[MT / 32], wf[4];
#pragma unroll
    for (int i = 0; i < MT / 32; ++i) af[i] = *(const bf16x8*)(fa + i * 512);
#pragma unroll
    for (int i = 0; i < 4; ++i) wf[i] = *(const bf16x8*)(fw + i * 512);
#pragma unroll
    for (int mi = 0; mi < MT / 32; ++mi)
#pragma unroll
      for (int ni = 0; ni < 4; ++ni)
        acc[mi * 4 + ni] =
            __builtin_amdgcn_mfma_f32_16x16x32_bf16(af[mi], wf[ni], acc[mi * 4 + ni], 0, 0, 0);

    asm volatile("" ::: "memory");
    __builtin_amdgcn_s_barrier();
    asm volatile("" ::: "memory");
  }
}

// OUTMODE 0: C bf16 row-major [*,N]. 1: CT bf16 transposed CT[col*TM+row]
// (CT may be pre-offset). 2: Cf f32 row-major + bias.
template<int MT, int OUTMODE>
__device__ __forceinline__ void gemm_body(const ushort* __restrict__ A,
                                          const ushort* __restrict__ W,
                                          ushort* __restrict__ C,
                                          ushort* __restrict__ CT,
                                          float* __restrict__ Cf,
                                          const float* __restrict__ bias,
                                          int mt, int nt, int N, long TM,
                                          ushort* lds) {
  f32x4 acc[(MT / 32) * 4];
#pragma unroll
  for (int i = 0; i < (MT / 32) * 4; ++i) acc[i] = (f32x4){0, 0, 0, 0};
  gemm_mac<MT>(A, W, mt, nt, lds, acc);

  int lane = threadIdx.x & 63, l15 = lane & 15, kg = lane >> 4;
  int wv = threadIdx.x >> 6;
  int Rw = mt * MT + (wv >> 1) * (MT / 2);
  int Cw = nt * 128 + (wv & 1) * 64;
#pragma unroll
  for (int mi = 0; mi < MT / 32; ++mi) {
    int row = Rw + mi * 16 + kg * 4;
#pragma unroll
    for (int ni = 0; ni < 4; ++ni) {
      f32x4 v = acc[mi * 4 + ni];
      int col = Cw + ni * 16 + l15;
      if (OUTMODE == 0) {
#pragma unroll
        for (int r = 0; r < 4; ++r) C[(size_t)(row + r) * N + col] = f2bf(v[r]);
      } else if (OUTMODE == 1) {
        ushort4 o = { f2bf(v[0]), f2bf(v[1]), f2bf(v[2]), f2bf(v[3]) };
        *(ushort4*)(CT + (long)col * TM + row) = o;
      } else {
        float bv = bias[col];
#pragma unroll
        for (int r = 0; r < 4; ++r) Cf[(size_t)(row + r) * N + col] = v[r] + bv;
      }
    }
  }
}

// Fused input GEMMs. blocks [0,288): qkv = x@qkv_w.T (24m x 12n tiles;
// n-tiles >=8 are self-V cols -> transposed into vselfT).
// [288,416): kctx (32x4). [416,544): vctx^T (32x4). kctx/vctx tiles whose
// BOTH covered frames are masked exit before staging (never read by flash).
__global__ __launch_bounds__(256) void gemm3(const ushort* __restrict__ xb,
                                             const ushort* __restrict__ dxb,
                                             const ushort* __restrict__ xcb,
                                             const ushort* __restrict__ qkvwb,
                                             const ushort* __restrict__ kwb,
                                             const ushort* __restrict__ vwb,
                                             const int* __restrict__ ctx_mask,
                                             ushort* __restrict__ qkv,
                                             ushort* __restrict__ vselfT,
                                             ushort* __restrict__ kctx,
                                             ushort* __restrict__ vctxT) {
  __shared__ ushort lds[24576];   // 3 bufs x (A 8KB + W 8KB) = 48 KB
  int blk = blockIdx.x;
  if (blk < 288) {
    int mt = blk % 24, nt = blk / 24;
    if (nt < 8)
      gemm_body<128, 0>(xb, qkvwb, qkv, nullptr, nullptr, nullptr, mt, nt, 1536, 0, lds);
    else
      gemm_body<128, 1>(xb, qkvwb, nullptr, vselfT - (size_t)1024 * 3072, nullptr, nullptr,
                        mt, nt, 1536, 3072, lds);
  } else if (blk < 416) {
    int r = blk - 288;
    int mt = r % 32, nt = r / 32;
    int bb = mt >> 3, f0 = (mt & 7) << 1;
    if (ctx_mask[bb * TT + f0] == 0 && ctx_mask[bb * TT + f0 + 1] == 0) return;
    gemm_body<128, 0>(dxb, kwb, kctx, nullptr, nullptr, nullptr, mt, nt, 512, 0, lds);
  } else {
    int r = blk - 416;
    int mt = r % 32, nt = r / 32;
    int bb = mt >> 3, f0 = (mt & 7) << 1;
    if (ctx_mask[bb * TT + f0] == 0 && ctx_mask[bb * TT + f0 + 1] == 0) return;
    gemm_body<128, 1>(xcb, vwb, nullptr, vctxT, nullptr, nullptr, mt, nt, 512, 4096, lds);
  }
}

// proj: 64-row tiles -> 192 blocks (48 mt x 4 nt).
__global__ __launch_bounds__(256) void gemm_proj(const ushort* __restrict__ aout,
                                                 const ushort* __restrict__ pwb,
                                                 const float* __restrict__ bias,
                                                 float* __restrict__ out) {
  __shared__ ushort lds[18432];   // 3 bufs x (A 4KB + W 8KB) = 36 KB
  int blk = blockIdx.x;
  gemm_body<64, 2>(aout, pwb, nullptr, nullptr, out, bias, blk % 48, blk / 48, 512, 0, lds);
}

// One attention tile for a 32-query wave: one K/V fragment stream feeds TWO
// 16-query S^T/PV chains (halves K/V L2 traffic per query). [R11-proven]
__device__ __forceinline__ void attn_tile32(const ushort* __restrict__ kbase, int kstr,
                                            const ushort* __restrict__ vtb, int vtN,
                                            bf16x8 qa0, bf16x8 qa1,
                                            bf16x8 qb0, bf16x8 qb1,
                                            int l15, int kg,
                                            ushort* __restrict__ Pt,
                                            f32x4 (*acc)[4], float* Lacc) {
  f32x4 s[2][4];
#pragma unroll
  for (int st = 0; st < 4; ++st) {
    const ushort* kp = kbase + (size_t)(st * 16 + l15) * kstr + kg * 8;
    bf16x8 k0 = *(const bf16x8*)kp;
    bf16x8 k1 = *(const bf16x8*)(kp + 32);
    f32x4 z0 = {0, 0, 0, 0}, z1 = {0, 0, 0, 0};
    z0 = __builtin_amdgcn_mfma_f32_16x16x32_bf16(k0, qa0, z0, 0, 0, 0);
    z0 = __builtin_amdgcn_mfma_f32_16x16x32_bf16(k1, qa1, z0, 0, 0, 0);
    z1 = __builtin_amdgcn_mfma_f32_16x16x32_bf16(k0, qb0, z1, 0, 0, 0);
    z1 = __builtin_amdgcn_mfma_f32_16x16x32_bf16(k1, qb1, z1, 0, 0, 0);
    s[0][st] = z0;
    s[1][st] = z1;
  }
#pragma unroll
  for (int qf = 0; qf < 2; ++qf) {
#pragma unroll
    for (int st = 0; st < 4; ++st) {
      float p0 = __builtin_exp2f(fmaf(s[qf][st][0], 0.18033688f, -23.0831206f));
      float p1 = __builtin_exp2f(fmaf(s[qf][st][1], 0.18033688f, -23.0831206f));
      float p2 = __builtin_exp2f(fmaf(s[qf][st][2], 0.18033688f, -23.0831206f));
      float p3 = __builtin_exp2f(fmaf(s[qf][st][3], 0.18033688f, -23.0831206f));
      Lacc[qf] += (p0 + p1) + (p2 + p3);
      ushort4 pk = { f2bf(p0), f2bf(p1), f2bf(p2), f2bf(p3) };
      *(ushort4*)(Pt + qf * 1152 + l15 * 72 + st * 16 + kg * 4) = pk;
    }
  }
#pragma unroll
  for (int kc = 0; kc < 2; ++kc) {
    bf16x8 pb0 = *(const bf16x8*)(Pt + l15 * 72 + kc * 32 + kg * 8);
    bf16x8 pb1 = *(const bf16x8*)(Pt + 1152 + l15 * 72 + kc * 32 + kg * 8);
#pragma unroll
    for (int d = 0; d < 4; ++d) {
      const ushort* vp = vtb + (size_t)(d * 16 + l15) * vtN + kc * 32 + kg * 8;
      bf16x8 vf = *(const bf16x8*)vp;
      acc[0][d] = __builtin_amdgcn_mfma_f32_16x16x32_bf16(vf, pb0, acc[0][d], 0, 0, 0);
      acc[1][d] = __builtin_amdgcn_mfma_f32_16x16x32_bf16(vf, pb1, acc[1][d], 0, 0, 0);
    }
  }
}

// Flash attention, fixed-M streaming softmax, 4-way split-K, 32-query waves.
// Block = (b, h, t0): 384 blocks x 512 threads = 2 q-halves x 4 key-splits.
// [R11-proven configuration]
__global__ __launch_bounds__(512, 4) void flash_attn(const ushort* __restrict__ qkv,
                                                     const ushort* __restrict__ kctx,
                                                     const ushort* __restrict__ vctxT,
                                                     const ushort* __restrict__ vselfT,
                                                     const int* __restrict__ ctx_mask,
                                                     ushort* __restrict__ aout) {
  __shared__ float smem[13056];      // 52.2 KB; Pt strips (36 KB) alias low part
  int blk = blockIdx.x;              // b*96 + h*12 + t0
  int t0 = blk % NT0;
  int h  = (blk / NT0) % HH;
  int b  = blk / (NT0 * HH);
  int tid = threadIdx.x, wv = tid >> 6, lane = tid & 63;
  int qg = wv >> 2, ks = wv & 3;     // qg: 32-query half; ks: key split
  int l15 = lane & 15, kg = lane >> 4;

  int qbase = b * NQ + t0 * LL + qg * 32;
  const ushort* qp0 = qkv + (size_t)(qbase + l15) * 1536 + h * HD + kg * 8;
  const ushort* qp1 = qkv + (size_t)(qbase + 16 + l15) * 1536 + h * HD + kg * 8;
  bf16x8 qa0 = *(const bf16x8*)qp0;
  bf16x8 qa1 = *(const bf16x8*)(qp0 + 32);
  bf16x8 qb0 = *(const bf16x8*)qp1;
  bf16x8 qb1 = *(const bf16x8*)(qp1 + 32);

  f32x4 acc[2][4];
#pragma unroll
  for (int qf = 0; qf < 2; ++qf)
#pragma unroll
    for (int d = 0; d < 4; ++d) acc[qf][d] = (f32x4){0, 0, 0, 0};
  float Lacc[2] = {0.f, 0.f};
  ushort* Pt = (ushort*)smem + wv * 2304;  // 2 strips of 1152 (single-buffered)

  int kts[4]; int nkt = 0;
#pragma unroll
  for (int ki = 0; ki < 4; ++ki) {
    int kt = ks * 4 + ki;
    if (ctx_mask[b * TT + kt] != 0 && kt != t0 + 4) kts[nkt++] = kt;
  }

  const ushort* vctxb = vctxT + (size_t)h * HD * (BB * NCTX) + b * NCTX;
  for (int ki = 0; ki < nkt; ++ki) {
    int kt = kts[ki];
    attn_tile32(kctx + (size_t)(b * NCTX + kt * LL) * CC + h * HD, CC,
                vctxb + kt * LL, BB * NCTX,
                qa0, qa1, qb0, qb1, l15, kg, Pt, acc, Lacc);
  }
  if (ks == 0) {
    attn_tile32(qkv + (size_t)(b * NQ + t0 * LL) * 1536 + CC + h * HD, 1536,
                vselfT + (size_t)h * HD * (BB * NQ) + b * NQ + t0 * LL, BB * NQ,
                qa0, qa1, qb0, qb1, l15, kg, Pt, acc, Lacc);
  }

  float L0 = Lacc[0], L1 = Lacc[1];
  L0 += __shfl_xor(L0, 16, 64); L0 += __shfl_xor(L0, 32, 64);
  L1 += __shfl_xor(L1, 16, 64); L1 += __shfl_xor(L1, 32, 64);

  // ---- merge: ks1..3 publish (plain sums), ks0 adds & writes ----
  __syncthreads();
  if (ks) {
    float* reg = smem + (size_t)(qg * 3 + ks - 1) * 2176;  // 2048 acc + 128 L
#pragma unroll
    for (int qf = 0; qf < 2; ++qf)
#pragma unroll
      for (int d = 0; d < 4; ++d)
        *(f32x4*)(reg + (qf * 64 + lane) * 16 + d * 4) = acc[qf][d];
    reg[2048 + lane * 2]     = L0;
    reg[2048 + lane * 2 + 1] = L1;
  }
  __syncthreads();
  if (!ks) {
    float Ls[2] = {L0, L1};
    f32x4 o[2][4];
#pragma unroll
    for (int qf = 0; qf < 2; ++qf)
#pragma unroll
      for (int d = 0; d < 4; ++d) o[qf][d] = acc[qf][d];
#pragma unroll
    for (int j = 0; j < 3; ++j) {
      const float* reg = smem + (size_t)(qg * 3 + j) * 2176;
      Ls[0] += reg[2048 + lane * 2];
      Ls[1] += reg[2048 + lane * 2 + 1];
#pragma unroll
      for (int qf = 0; qf < 2; ++qf)
#pragma unroll
        for (int d = 0; d < 4; ++d)
          o[qf][d] += *(const f32x4*)(reg + (qf * 64 + lane) * 16 + d * 4);
    }
#pragma unroll
    for (int qf = 0; qf < 2; ++qf) {
      float inv = 1.f / Ls[qf];
      int orow = qbase + qf * 16 + l15;
#pragma unroll
      for (int d = 0; d < 4; ++d) {
        ushort4 ov = { f2bf(o[qf][d][0] * inv), f2bf(o[qf][d][1] * inv),
                       f2bf(o[qf][d][2] * inv), f2bf(o[qf][d][3] * inv) };
        *(ushort4*)(aout + (size_t)orow * CC + h * HD + d * 16 + kg * 4) = ov;
      }
    }
  }
}

extern "C" void kernel_launch(void* const* d_in, const int* in_sizes, int n_in,
                              void* d_out, int out_size, void* d_ws, size_t ws_size,
                              hipStream_t stream) {
  const float* x        = (const float*)d_in[0];
  const float* x_ctx    = (const float*)d_in[1];
  const float* dx_ctx   = (const float*)d_in[2];
  const int*   ctx_mask = (const int*)d_in[3];
  const float* qkv_w    = (const float*)d_in[4];
  const float* k_w      = (const float*)d_in[5];
  const float* v_w      = (const float*)d_in[6];
  const float* proj_w   = (const float*)d_in[7];
  const float* proj_b   = (const float*)d_in[8];
  float* out = (float*)d_out;

  ushort* ws = (ushort*)d_ws;   // element offsets (bf16)
  ushort* qkvwb  = ws;                    //  786432
  ushort* kwb    = ws + 786432;           //  262144
  ushort* vwb    = ws + 1048576;          //  262144
  ushort* pwb    = ws + 1310720;          //  262144
  ushort* xb     = ws + 1572864;          // 1572864  (3072x512)
  ushort* xcb    = ws + 3145728;          // 2097152  (4096x512)
  ushort* dxb    = ws + 5242880;          // 2097152  (4096x512)
  ushort* qkv    = ws + 7340032;          // 3072x1536
  ushort* kctx   = ws + 12058624;         // 4096x512
  ushort* vctxT  = ws + 14155776;         // 512x4096
  ushort* vselfT = ws + 16252928;         // 512x3072
  ushort* aout   = ws + 17825792;         // 3072x512  (end 19398656 el = 38.8MB)

  cvt_all<<<7168, 256, 0, stream>>>(qkv_w, k_w, v_w, proj_w, x, x_ctx, dx_ctx,
                                    ctx_mask, ws);
  gemm3<<<544, 256, 0, stream>>>(xb, dxb, xcb, qkvwb, kwb, vwb, ctx_mask,
                                 qkv, vselfT, kctx, vctxT);
  flash_attn<<<384, 512, 0, stream>>>(qkv, kctx, vctxT, vselfT, ctx_mask, aout);
  gemm_proj<<<192, 256, 0, stream>>>(aout, pwb, proj_b, out);
}